// Round 4
// baseline (554.570 us; speedup 1.0000x reference)
//
#include <hip/hip_runtime.h>
#include <cstdint>

using s8v = __attribute__((ext_vector_type(8))) short;
using f4v = __attribute__((ext_vector_type(4))) float;

__device__ __forceinline__ float sigmoidf_(float x) {
  return 1.0f / (1.0f + __expf(-x));
}
__device__ __forceinline__ float tanhf_(float x) {
  return 2.0f / (1.0f + __expf(-2.0f * x)) - 1.0f;
}

__device__ __forceinline__ unsigned short bf16_rne(float x) {
  unsigned u = __builtin_bit_cast(unsigned, x);
  unsigned r = (u + 0x7FFF + ((u >> 16) & 1)) >> 16;
  return (unsigned short)r;
}
__device__ __forceinline__ float bf16_to_f32(unsigned short s) {
  unsigned u = ((unsigned)s) << 16;
  return __builtin_bit_cast(float, u);
}

// h[i][j] = emb[x[i]][j]
__global__ __launch_bounds__(256) void k_embed(const int* __restrict__ x,
                                               const float* __restrict__ emb,
                                               float* __restrict__ h, int N) {
  int idx = blockIdx.x * 256 + threadIdx.x;
  if (idx >= N * 64) return;
  int i = idx >> 6, j = idx & 63;
  h[idx] = emb[x[i] * 64 + j];
}

__global__ __launch_bounds__(256) void k_count(const int* __restrict__ dst,
                                               int* __restrict__ cnt, int E) {
  int e = blockIdx.x * 256 + threadIdx.x;
  if (e < E) atomicAdd(&cnt[dst[e]], 1);
}

__global__ __launch_bounds__(256) void k_scan1(const int* __restrict__ cnt,
                                               int* __restrict__ part, int N) {
  __shared__ int s[256];
  int i = blockIdx.x * 256 + threadIdx.x;
  s[threadIdx.x] = (i < N) ? cnt[i] : 0;
  __syncthreads();
  for (int off = 128; off > 0; off >>= 1) {
    if (threadIdx.x < off) s[threadIdx.x] += s[threadIdx.x + off];
    __syncthreads();
  }
  if (threadIdx.x == 0) part[blockIdx.x] = s[0];
}

__global__ __launch_bounds__(512) void k_scan2(const int* __restrict__ part,
                                               int* __restrict__ coff, int nC) {
  __shared__ int s[512];
  int t = threadIdx.x;
  int v = (t < nC) ? part[t] : 0;
  s[t] = v;
  __syncthreads();
  for (int off = 1; off < 512; off <<= 1) {
    int xx = (t >= off) ? s[t - off] : 0;
    __syncthreads();
    s[t] += xx;
    __syncthreads();
  }
  if (t < nC) coff[t] = s[t] - v;  // exclusive prefix
}

__global__ __launch_bounds__(256) void k_scan3(const int* __restrict__ cnt,
                                               const int* __restrict__ coff,
                                               int* __restrict__ rowp, int N, int E) {
  __shared__ int s[256];
  int t = threadIdx.x;
  int i = blockIdx.x * 256 + t;
  int v = (i < N) ? cnt[i] : 0;
  s[t] = v;
  __syncthreads();
  for (int off = 1; off < 256; off <<= 1) {
    int xx = (t >= off) ? s[t - off] : 0;
    __syncthreads();
    s[t] += xx;
    __syncthreads();
  }
  if (i < N) rowp[i] = coff[blockIdx.x] + s[t] - v;
  if (blockIdx.x == 0 && t == 0) rowp[N] = E;
}

__global__ __launch_bounds__(256) void k_fill(const int* __restrict__ src,
                                              const int* __restrict__ dst,
                                              const int* __restrict__ rowp,
                                              int* __restrict__ cur,
                                              int* __restrict__ ssrc, int E) {
  int e = blockIdx.x * 256 + threadIdx.x;
  if (e >= E) return;
  int d = dst[e];
  int pos = rowp[d] + atomicAdd(&cur[d], 1);
  ssrc[pos] = src[e];
}

// Fused Wp = wih @ ggc^T fold + MFMA-fragment pack, split bf16 hi/lo.
// New gate-major frag layout: idx = (((w*4+g)*4+t)*64+lane)*8+i holds
// B[32t + 8*(lane>>4) + i][gate g, col 16w + (lane&15)] where
// B[k][g,j] = (k<64) ? Wp[64g'+j][k] : whh[64g''+j][k-64]
//   g=0: r (Wp row j   ; whh row j),    g=1: z (Wp 64+j ; whh 64+j),
//   g=2: inn (Wp 128+j ; 0),            g=3: hn (0      ; whh 128+j)
// and Wp[r][k] = sum_m wih[r][m] * ggc[k][m]  (ggc_W fold).
__global__ __launch_bounds__(256) void k_wpack(const float* __restrict__ wih,
                                               const float* __restrict__ ggc,
                                               const float* __restrict__ whh,
                                               unsigned short* __restrict__ Bhi,
                                               unsigned short* __restrict__ Blo) {
  int tid = blockIdx.x * 256 + threadIdx.x;
  if (tid >= 4096) return;
  int lane = tid & 63;
  int t = (tid >> 6) & 3;
  int wg = tid >> 8;
  int g = wg & 3, w = wg >> 2;
  int j = 16 * w + (lane & 15);
  int kbase = t * 32 + (lane >> 4) * 8;
  unsigned short hi[8], lo[8];
#pragma unroll
  for (int i = 0; i < 8; ++i) {
    int k = kbase + i;
    float v = 0.0f;
    if (k < 64) {
      if (g < 3) {
        const float* a = wih + (size_t)(g * 64 + j) * 64;
        const float* b = ggc + (size_t)k * 64;
        float s = 0.0f;
#pragma unroll
        for (int m = 0; m < 64; ++m) s += a[m] * b[m];
        v = s;
      }
    } else {
      if (g != 2) {
        int row = (g == 3 ? 2 : g) * 64 + j;
        v = whh[(size_t)row * 64 + (k - 64)];
      }
    }
    hi[i] = bf16_rne(v);
    lo[i] = bf16_rne(v - bf16_to_f32(hi[i]));
  }
#pragma unroll
  for (int i = 0; i < 8; ++i) {
    Bhi[(size_t)tid * 8 + i] = hi[i];
    Blo[(size_t)tid * 8 + i] = lo[i];
  }
}

__device__ __forceinline__ void f32x8_to_split(const float* __restrict__ p,
                                               s8v& hi, s8v& lo) {
  f4v x0 = *(const f4v*)p;
  f4v x1 = *(const f4v*)(p + 4);
#pragma unroll
  for (int i = 0; i < 4; ++i) {
    unsigned short hs = bf16_rne(x0[i]);
    hi[i] = (short)hs;
    lo[i] = (short)bf16_rne(x0[i] - bf16_to_f32(hs));
  }
#pragma unroll
  for (int i = 0; i < 4; ++i) {
    unsigned short hs = bf16_rne(x1[i]);
    hi[4 + i] = (short)hs;
    lo[4 + i] = (short)bf16_rne(x1[i] - bf16_to_f32(hs));
  }
}

#define ASTRIDE 68  // 64 + 4 pad

// Fused CSR-gather + GRU (split-bf16 MFMA), gate-major C tiles -> in-register
// epilogue (no gate-exchange LDS, no second barrier). Ping-pong hin/hout.
__global__ __launch_bounds__(256, 3) void k_gfu(const float* __restrict__ hin,
                                                float* __restrict__ hout,
                                                const int* __restrict__ rowp,
                                                const int* __restrict__ ssrc,
                                                const unsigned short* __restrict__ Bhi,
                                                const unsigned short* __restrict__ Blo,
                                                const float* __restrict__ bih,
                                                const float* __restrict__ bhh,
                                                int N, int nTiles) {
  __shared__ float aggLds[16 * ASTRIDE];
  __shared__ float hLds[16 * ASTRIDE];
  const int lane = threadIdx.x & 63;
  const int w = threadIdx.x >> 6;
  const int r15 = lane & 15;
  const int kg8 = (lane >> 4) * 8;
  const int jj = w * 16 + r15;  // this lane's output column (fixed)

  // per-column gate biases (fixed per lane)
  const float b_r = bih[jj] + bhh[jj];
  const float b_z = bih[64 + jj] + bhh[64 + jj];
  const float b_i = bih[128 + jj];
  const float b_h = bhh[128 + jj];

  // Register-resident B fragments: 4 gates x 4 k-slices for cols [16w,16w+16)
  s8v bh_[4][4], bl_[4][4];
#pragma unroll
  for (int g = 0; g < 4; ++g) {
#pragma unroll
    for (int t = 0; t < 4; ++t) {
      size_t idx = ((size_t)(((w * 4 + g) * 4 + t)) * 64 + lane) * 8;
      bh_[g][t] = *(const s8v*)(Bhi + idx);
      bl_[g][t] = *(const s8v*)(Blo + idx);
    }
  }

  for (int tile = blockIdx.x; tile < nTiles; tile += gridDim.x) {
    const int n0 = tile * 16;
    // ---- gather + h staging (each 16-lane group owns one node) ----
    {
      const int g = lane >> 4;
      const int node = 4 * w + g;
      const int n = n0 + node;
      const int nc = min(n, N - 1);
      f4v hv = *(const f4v*)(hin + (size_t)nc * 64 + 4 * r15);
      f4v a0 = {0, 0, 0, 0}, a1 = {0, 0, 0, 0}, a2 = {0, 0, 0, 0}, a3 = {0, 0, 0, 0};
      if (n < N) {
        int e = rowp[n];
        const int end = rowp[n + 1];
        for (; e + 4 <= end; e += 4) {
          int s0 = ssrc[e], s1 = ssrc[e + 1], s2 = ssrc[e + 2], s3 = ssrc[e + 3];
          a0 += *(const f4v*)(hin + (size_t)s0 * 64 + 4 * r15);
          a1 += *(const f4v*)(hin + (size_t)s1 * 64 + 4 * r15);
          a2 += *(const f4v*)(hin + (size_t)s2 * 64 + 4 * r15);
          a3 += *(const f4v*)(hin + (size_t)s3 * 64 + 4 * r15);
        }
        if (e + 2 <= end) {
          int s0 = ssrc[e], s1 = ssrc[e + 1];
          a0 += *(const f4v*)(hin + (size_t)s0 * 64 + 4 * r15);
          a1 += *(const f4v*)(hin + (size_t)s1 * 64 + 4 * r15);
          e += 2;
        }
        if (e < end) {
          int s0 = ssrc[e];
          a2 += *(const f4v*)(hin + (size_t)s0 * 64 + 4 * r15);
        }
      }
      a0 += a1; a2 += a3; a0 += a2;
      *(f4v*)(aggLds + node * ASTRIDE + 4 * r15) = a0;
      *(f4v*)(hLds + node * ASTRIDE + 4 * r15) = hv;
    }
    __syncthreads();

    // ---- A fragments from LDS (split bf16), rows = 16 nodes ----
    s8v ah[4], al[4];
#pragma unroll
    for (int t = 0; t < 2; ++t)
      f32x8_to_split(aggLds + r15 * ASTRIDE + t * 32 + kg8, ah[t], al[t]);
#pragma unroll
    for (int t = 0; t < 2; ++t)
      f32x8_to_split(hLds + r15 * ASTRIDE + t * 32 + kg8, ah[2 + t], al[2 + t]);

    f4v acc[4];
#pragma unroll
    for (int g = 0; g < 4; ++g) acc[g] = (f4v){0.0f, 0.0f, 0.0f, 0.0f};
#pragma unroll
    for (int t = 0; t < 4; ++t) {
#pragma unroll
      for (int g = 0; g < 4; ++g) {
        acc[g] = __builtin_amdgcn_mfma_f32_16x16x32_bf16(ah[t], bh_[g][t], acc[g], 0, 0, 0);
        acc[g] = __builtin_amdgcn_mfma_f32_16x16x32_bf16(ah[t], bl_[g][t], acc[g], 0, 0, 0);
        acc[g] = __builtin_amdgcn_mfma_f32_16x16x32_bf16(al[t], bh_[g][t], acc[g], 0, 0, 0);
      }
    }

    // ---- in-register epilogue: C row = (lane>>4)*4 + q, col = jj [m89] ----
    const int rb = (lane >> 4) * 4;
#pragma unroll
    for (int q = 0; q < 4; ++q) {
      int row = rb + q;
      int n = n0 + row;
      if (n < N) {
        float hold = hLds[row * ASTRIDE + jj];
        float r = sigmoidf_(acc[0][q] + b_r);
        float z = sigmoidf_(acc[1][q] + b_z);
        float nv = tanhf_(acc[2][q] + b_i + r * (acc[3][q] + b_h));
        float o = (1.0f - z) * nv + z * hold;
        hout[(size_t)n * 64 + jj] = fmaxf(o, 0.0f);
      }
    }
    __syncthreads();
  }
}

// segment-mean pooling over sorted batch ids (per-wave local accumulate, atomic flush)
__global__ __launch_bounds__(256) void k_pool(const float* __restrict__ h,
                                              const int* __restrict__ batch,
                                              float* __restrict__ psum,
                                              float* __restrict__ pcnt, int N) {
  int lane = threadIdx.x & 63;
  int wid = blockIdx.x * 4 + (threadIdx.x >> 6);
  int base = wid * 64;
  if (base >= N) return;
  int endn = min(base + 64, N);
  float acc = 0.0f, ca = 0.0f;
  int curb = batch[base];
  for (int nn = base; nn < endn; ++nn) {
    int b = batch[nn];
    if (b != curb) {
      atomicAdd(&psum[curb * 64 + lane], acc);
      if (lane == 0) atomicAdd(&pcnt[curb], ca);
      acc = 0.0f; ca = 0.0f; curb = b;
    }
    acc += h[(size_t)nn * 64 + lane];
    ca += 1.0f;
  }
  atomicAdd(&psum[curb * 64 + lane], acc);
  if (lane == 0) atomicAdd(&pcnt[curb], ca);
}

// MLP head: 64 -> 32 -> 16 -> 1, one 64-thread block per batch element
__global__ __launch_bounds__(64) void k_head(const float* __restrict__ psum,
                                             const float* __restrict__ pcnt,
                                             const float* __restrict__ fc1W,
                                             const float* __restrict__ fc1b,
                                             const float* __restrict__ fc2W,
                                             const float* __restrict__ fc2b,
                                             const float* __restrict__ fc3W,
                                             const float* __restrict__ fc3b,
                                             float* __restrict__ out) {
  int b = blockIdx.x;
  int j = threadIdx.x;
  float c = fmaxf(pcnt[b], 1.0f);
  float p = psum[b * 64 + j] / c;
  int j1 = j & 31;
  float y1 = fc1b[j1];
#pragma unroll
  for (int k = 0; k < 64; ++k) y1 += fc1W[j1 * 64 + k] * __shfl(p, k, 64);
  y1 = fmaxf(y1, 0.0f);
  int j2 = j & 15;
  float y2 = fc2b[j2];
#pragma unroll
  for (int k = 0; k < 32; ++k) y2 += fc2W[j2 * 32 + k] * __shfl(y1, k, 64);
  y2 = fmaxf(y2, 0.0f);
  float y = 0.0f;
#pragma unroll
  for (int k = 0; k < 16; ++k) y += fc3W[k] * __shfl(y2, k, 64);
  if (j == 0) out[b] = y + fc3b[0];
}

extern "C" void kernel_launch(void* const* d_in, const int* in_sizes, int n_in,
                              void* d_out, int out_size, void* d_ws, size_t ws_size,
                              hipStream_t stream) {
  const int N = in_sizes[0];
  const int E = in_sizes[1] / 2;
  const int B = out_size;

  const int* x = (const int*)d_in[0];
  const int* eidx = (const int*)d_in[1];
  const int* batch = (const int*)d_in[3];
  const float* emb = (const float*)d_in[4];
  const float* ggcW = (const float*)d_in[7];
  const float* wih = (const float*)d_in[8];
  const float* whh = (const float*)d_in[9];
  const float* bih = (const float*)d_in[10];
  const float* bhh = (const float*)d_in[11];
  const float* fc1W = (const float*)d_in[12];
  const float* fc1b = (const float*)d_in[13];
  const float* fc2W = (const float*)d_in[14];
  const float* fc2b = (const float*)d_in[15];
  const float* fc3W = (const float*)d_in[16];
  const float* fc3b = (const float*)d_in[17];
  float* out = (float*)d_out;

  const int* srcp = eidx;
  const int* dstp = eidx + E;

  char* ws = (char*)d_ws;
  size_t off = 0;
  auto alloc = [&](size_t bytes) -> void* {
    void* p = ws + off;
    off = (off + bytes + 255) & ~(size_t)255;
    return p;
  };
  float* h0 = (float*)alloc((size_t)N * 64 * 4);
  float* h1 = (float*)alloc((size_t)N * 64 * 4);
  int* rowp = (int*)alloc((size_t)(N + 1) * 4);
  int* cur = (int*)alloc((size_t)N * 4);
  int* ssrc = (int*)alloc((size_t)E * 4);
  const int nC = (N + 255) / 256;
  int* part = (int*)alloc((size_t)nC * 4);
  int* coff = (int*)alloc((size_t)nC * 4);
  unsigned short* Bhi = (unsigned short*)alloc((size_t)4096 * 8 * 2);
  unsigned short* Blo = (unsigned short*)alloc((size_t)4096 * 8 * 2);
  float* pool = (float*)alloc((size_t)(B * 64 + B) * 4);
  float* psum = pool;
  float* pcnt = pool + (size_t)B * 64;

  // --- build CSR (dst-sorted edge list), once per launch ---
  hipMemsetAsync(cur, 0, (size_t)N * 4, stream);
  k_embed<<<(N * 64 + 255) / 256, 256, 0, stream>>>(x, emb, h0, N);
  k_count<<<(E + 255) / 256, 256, 0, stream>>>(dstp, cur, E);
  k_scan1<<<nC, 256, 0, stream>>>(cur, part, N);
  k_scan2<<<1, 512, 0, stream>>>(part, coff, nC);
  k_scan3<<<nC, 256, 0, stream>>>(cur, coff, rowp, N, E);
  hipMemsetAsync(cur, 0, (size_t)N * 4, stream);
  k_fill<<<(E + 255) / 256, 256, 0, stream>>>(srcp, dstp, rowp, cur, ssrc, E);

  const int nTiles = (N + 15) / 16;
  const int grid = nTiles < 2048 ? nTiles : 2048;
  // --- 3 fused GGC+GRU layers (ggc_W folded into GRU input weights) ---
  float* hb[2] = {h0, h1};
  for (int l = 0; l < 3; ++l) {
    k_wpack<<<16, 256, 0, stream>>>(wih + (size_t)l * 192 * 64,
                                    ggcW + (size_t)l * 64 * 64,
                                    whh + (size_t)l * 192 * 64, Bhi, Blo);
    k_gfu<<<grid, 256, 0, stream>>>(hb[l & 1], hb[1 - (l & 1)], rowp, ssrc,
                                    Bhi, Blo, bih + (size_t)l * 192,
                                    bhh + (size_t)l * 192, N, nTiles);
  }
  float* hfin = hb[1];  // after 3 layers: h0->h1->h0->h1

  // --- mean pool + MLP head ---
  hipMemsetAsync(pool, 0, (size_t)(B * 64 + B) * 4, stream);
  int nwaves = (N + 63) / 64;
  k_pool<<<(nwaves + 3) / 4, 256, 0, stream>>>(hfin, batch, psum, pcnt, N);
  k_head<<<B, 64, 0, stream>>>(psum, pcnt, fc1W, fc1b, fc2W, fc2b, fc3W, fc3b, out);
}

// Round 5
// 305.512 us; speedup vs baseline: 1.8152x; 1.8152x over previous
//
#include <hip/hip_runtime.h>
#include <cstdint>

using h8v = __attribute__((ext_vector_type(8))) _Float16;
using h4v = __attribute__((ext_vector_type(4))) _Float16;
using f4v = __attribute__((ext_vector_type(4))) float;

__device__ __forceinline__ float sigmoidf_(float x) {
  return 1.0f / (1.0f + __expf(-x));
}
__device__ __forceinline__ float tanhf_(float x) {
  return 2.0f / (1.0f + __expf(-2.0f * x)) - 1.0f;
}

// h[i][j] = emb[x[i]][j]  (f32 plane + fp16 plane)
__global__ __launch_bounds__(256) void k_embed(const int* __restrict__ x,
                                               const float* __restrict__ emb,
                                               float* __restrict__ h,
                                               _Float16* __restrict__ h16, int N) {
  int idx = blockIdx.x * 256 + threadIdx.x;
  if (idx >= N * 64) return;
  int i = idx >> 6, j = idx & 63;
  float v = emb[x[i] * 64 + j];
  h[idx] = v;
  h16[idx] = (_Float16)v;
}

__global__ __launch_bounds__(256) void k_count(const int* __restrict__ dst,
                                               int* __restrict__ cnt, int E) {
  int e = blockIdx.x * 256 + threadIdx.x;
  if (e < E) atomicAdd(&cnt[dst[e]], 1);
}

__global__ __launch_bounds__(256) void k_scan1(const int* __restrict__ cnt,
                                               int* __restrict__ part, int N) {
  __shared__ int s[256];
  int i = blockIdx.x * 256 + threadIdx.x;
  s[threadIdx.x] = (i < N) ? cnt[i] : 0;
  __syncthreads();
  for (int off = 128; off > 0; off >>= 1) {
    if (threadIdx.x < off) s[threadIdx.x] += s[threadIdx.x + off];
    __syncthreads();
  }
  if (threadIdx.x == 0) part[blockIdx.x] = s[0];
}

__global__ __launch_bounds__(512) void k_scan2(const int* __restrict__ part,
                                               int* __restrict__ coff, int nC) {
  __shared__ int s[512];
  int t = threadIdx.x;
  int v = (t < nC) ? part[t] : 0;
  s[t] = v;
  __syncthreads();
  for (int off = 1; off < 512; off <<= 1) {
    int xx = (t >= off) ? s[t - off] : 0;
    __syncthreads();
    s[t] += xx;
    __syncthreads();
  }
  if (t < nC) coff[t] = s[t] - v;  // exclusive prefix
}

__global__ __launch_bounds__(256) void k_scan3(const int* __restrict__ cnt,
                                               const int* __restrict__ coff,
                                               int* __restrict__ rowp, int N, int E) {
  __shared__ int s[256];
  int t = threadIdx.x;
  int i = blockIdx.x * 256 + t;
  int v = (i < N) ? cnt[i] : 0;
  s[t] = v;
  __syncthreads();
  for (int off = 1; off < 256; off <<= 1) {
    int xx = (t >= off) ? s[t - off] : 0;
    __syncthreads();
    s[t] += xx;
    __syncthreads();
  }
  if (i < N) rowp[i] = coff[blockIdx.x] + s[t] - v;
  if (blockIdx.x == 0 && t == 0) rowp[N] = E;
}

__global__ __launch_bounds__(256) void k_fill(const int* __restrict__ src,
                                              const int* __restrict__ dst,
                                              const int* __restrict__ rowp,
                                              int* __restrict__ cur,
                                              int* __restrict__ ssrc, int E) {
  int e = blockIdx.x * 256 + threadIdx.x;
  if (e >= E) return;
  int d = dst[e];
  int pos = rowp[d] + atomicAdd(&cur[d], 1);
  ssrc[pos] = src[e];
}

// All-3-layers Wp fold + fp16 MFMA-fragment pack, gate-major.
// Per layer: idx = (((w*4+g)*4+t)*64+lane)*8+i holds
// B[32t + 8*(lane>>4) + i][gate g, col 16w + (lane&15)],
// B[k][g,j] = (k<64) ? Wp[64g'+j][k] : whh[64g''+j][k-64]
//   g=0: r (Wp j ; whh j),  g=1: z (Wp 64+j ; whh 64+j),
//   g=2: inn (Wp 128+j ; 0),  g=3: hn (0 ; whh 128+j)
// Wp[r][k] = sum_m wih[r][m] * ggc[k][m].
__global__ __launch_bounds__(256) void k_wpack3(const float* __restrict__ wih_all,
                                                const float* __restrict__ ggc_all,
                                                const float* __restrict__ whh_all,
                                                _Float16* __restrict__ Bp) {
  int l = blockIdx.x >> 4;  // layer
  int tid = (blockIdx.x & 15) * 256 + threadIdx.x;
  const float* wih = wih_all + (size_t)l * 192 * 64;
  const float* ggc = ggc_all + (size_t)l * 64 * 64;
  const float* whh = whh_all + (size_t)l * 192 * 64;
  int lane = tid & 63;
  int t = (tid >> 6) & 3;
  int wg = tid >> 8;
  int g = wg & 3, w = wg >> 2;
  int j = 16 * w + (lane & 15);
  int kbase = t * 32 + (lane >> 4) * 8;
  _Float16 hv[8];
#pragma unroll
  for (int i = 0; i < 8; ++i) {
    int k = kbase + i;
    float v = 0.0f;
    if (k < 64) {
      if (g < 3) {
        const float* a = wih + (size_t)(g * 64 + j) * 64;
        const float* b = ggc + (size_t)k * 64;
        float s = 0.0f;
#pragma unroll
        for (int m = 0; m < 64; ++m) s += a[m] * b[m];
        v = s;
      }
    } else {
      if (g != 2) {
        int row = (g == 3 ? 2 : g) * 64 + j;
        v = whh[(size_t)row * 64 + (k - 64)];
      }
    }
    hv[i] = (_Float16)v;
  }
  _Float16* o = Bp + (size_t)l * 32768 + (size_t)tid * 8;
#pragma unroll
  for (int i = 0; i < 8; ++i) o[i] = hv[i];
}

__device__ __forceinline__ h8v lds_to_h8(const float* __restrict__ p) {
  f4v x0 = *(const f4v*)p;
  f4v x1 = *(const f4v*)(p + 4);
  h8v r;
#pragma unroll
  for (int i = 0; i < 4; ++i) {
    r[i] = (_Float16)x0[i];
    r[4 + i] = (_Float16)x1[i];
  }
  return r;
}

#define ASTRIDE 68  // 64 + 4 pad

// Fused CSR-gather (fp16 plane) + GRU (fp16 MFMA, gate-major, in-register
// gates) + coalesced row stores via LDS exchange. last=1: fused mean-pool
// accumulate instead of h stores.
__global__ __launch_bounds__(256, 4) void k_gfu(const float* __restrict__ hin,
                                                const _Float16* __restrict__ hin16,
                                                float* __restrict__ hout,
                                                _Float16* __restrict__ hout16,
                                                const int* __restrict__ rowp,
                                                const int* __restrict__ ssrc,
                                                const _Float16* __restrict__ Bp,
                                                const float* __restrict__ bih,
                                                const float* __restrict__ bhh,
                                                const int* __restrict__ batch,
                                                float* __restrict__ psum,
                                                float* __restrict__ pcnt,
                                                int N, int nTiles, int last) {
  __shared__ float aggLds[16 * ASTRIDE];
  __shared__ float hLds[16 * ASTRIDE];
  __shared__ float oLds[16 * ASTRIDE];
  const int lane = threadIdx.x & 63;
  const int w = threadIdx.x >> 6;
  const int r15 = lane & 15;
  const int kg8 = (lane >> 4) * 8;
  const int jj = w * 16 + r15;  // this lane's output column

  const float b_r = bih[jj] + bhh[jj];
  const float b_z = bih[64 + jj] + bhh[64 + jj];
  const float b_i = bih[128 + jj];
  const float b_h = bhh[128 + jj];

  // Register-resident B fragments (zero blocks skipped):
  // g=0,1: t=0..3 ; g=2: t=0,1 ; g=3: t=2,3   -> 12 frags, 48 VGPR
  h8v b0[4], b1[4], b2[2], b3[2];
#pragma unroll
  for (int t = 0; t < 4; ++t) {
    b0[t] = *(const h8v*)(Bp + ((size_t)((w * 4 + 0) * 4 + t) * 64 + lane) * 8);
    b1[t] = *(const h8v*)(Bp + ((size_t)((w * 4 + 1) * 4 + t) * 64 + lane) * 8);
  }
#pragma unroll
  for (int t = 0; t < 2; ++t) {
    b2[t] = *(const h8v*)(Bp + ((size_t)((w * 4 + 2) * 4 + t) * 64 + lane) * 8);
    b3[t] = *(const h8v*)(Bp + ((size_t)((w * 4 + 3) * 4 + (2 + t)) * 64 + lane) * 8);
  }

  for (int tile = blockIdx.x; tile < nTiles; tile += gridDim.x) {
    const int n0 = tile * 16;
    __syncthreads();  // prev store phase done before restaging
    // ---- gather (fp16 rows) + h staging (each 16-lane group owns a node) ----
    {
      const int g = lane >> 4;
      const int node = 4 * w + g;
      const int n = n0 + node;
      const int nc = min(n, N - 1);
      f4v hv = *(const f4v*)(hin + (size_t)nc * 64 + 4 * r15);
      f4v a0 = {0, 0, 0, 0}, a1 = {0, 0, 0, 0}, a2 = {0, 0, 0, 0}, a3 = {0, 0, 0, 0};
      if (n < N) {
        int e = rowp[n];
        const int end = rowp[n + 1];
        for (; e + 4 <= end; e += 4) {
          int s0 = ssrc[e], s1 = ssrc[e + 1], s2 = ssrc[e + 2], s3 = ssrc[e + 3];
          a0 += __builtin_convertvector(*(const h4v*)(hin16 + (size_t)s0 * 64 + 4 * r15), f4v);
          a1 += __builtin_convertvector(*(const h4v*)(hin16 + (size_t)s1 * 64 + 4 * r15), f4v);
          a2 += __builtin_convertvector(*(const h4v*)(hin16 + (size_t)s2 * 64 + 4 * r15), f4v);
          a3 += __builtin_convertvector(*(const h4v*)(hin16 + (size_t)s3 * 64 + 4 * r15), f4v);
        }
        if (e + 2 <= end) {
          int s0 = ssrc[e], s1 = ssrc[e + 1];
          a0 += __builtin_convertvector(*(const h4v*)(hin16 + (size_t)s0 * 64 + 4 * r15), f4v);
          a1 += __builtin_convertvector(*(const h4v*)(hin16 + (size_t)s1 * 64 + 4 * r15), f4v);
          e += 2;
        }
        if (e < end) {
          int s0 = ssrc[e];
          a2 += __builtin_convertvector(*(const h4v*)(hin16 + (size_t)s0 * 64 + 4 * r15), f4v);
        }
      }
      a0 += a1; a2 += a3; a0 += a2;
      *(f4v*)(aggLds + node * ASTRIDE + 4 * r15) = a0;
      *(f4v*)(hLds + node * ASTRIDE + 4 * r15) = hv;
    }
    __syncthreads();

    // ---- A fragments (fp16) : t=0,1 from agg ; t=2,3 from h ----
    h8v ah[4];
#pragma unroll
    for (int t = 0; t < 2; ++t)
      ah[t] = lds_to_h8(aggLds + r15 * ASTRIDE + t * 32 + kg8);
#pragma unroll
    for (int t = 0; t < 2; ++t)
      ah[2 + t] = lds_to_h8(hLds + r15 * ASTRIDE + t * 32 + kg8);

    f4v acc0 = {0, 0, 0, 0}, acc1 = {0, 0, 0, 0}, acc2 = {0, 0, 0, 0}, acc3 = {0, 0, 0, 0};
#pragma unroll
    for (int t = 0; t < 4; ++t) {
      acc0 = __builtin_amdgcn_mfma_f32_16x16x32_f16(ah[t], b0[t], acc0, 0, 0, 0);
      acc1 = __builtin_amdgcn_mfma_f32_16x16x32_f16(ah[t], b1[t], acc1, 0, 0, 0);
    }
    acc2 = __builtin_amdgcn_mfma_f32_16x16x32_f16(ah[0], b2[0], acc2, 0, 0, 0);
    acc2 = __builtin_amdgcn_mfma_f32_16x16x32_f16(ah[1], b2[1], acc2, 0, 0, 0);
    acc3 = __builtin_amdgcn_mfma_f32_16x16x32_f16(ah[2], b3[0], acc3, 0, 0, 0);
    acc3 = __builtin_amdgcn_mfma_f32_16x16x32_f16(ah[3], b3[1], acc3, 0, 0, 0);

    // ---- in-register gates: C row = (lane>>4)*4 + q, col = jj [m89] ----
    const int rb = (lane >> 4) * 4;
#pragma unroll
    for (int q = 0; q < 4; ++q) {
      int row = rb + q;
      float hold = hLds[row * ASTRIDE + jj];
      float r = sigmoidf_(acc0[q] + b_r);
      float z = sigmoidf_(acc1[q] + b_z);
      float nv = tanhf_(acc2[q] + b_i + r * (acc3[q] + b_h));
      float o = (1.0f - z) * nv + z * hold;
      oLds[row * ASTRIDE + jj] = fmaxf(o, 0.0f);
    }
    __syncthreads();

    // ---- store phase ----
    if (!last) {
      // coalesced full-row stores: 16 threads cover one 256B row
      const int node = threadIdx.x >> 4;
      const int ci = (threadIdx.x & 15) * 4;
      const int n = n0 + node;
      if (n < N) {
        f4v o = *(const f4v*)(oLds + node * ASTRIDE + ci);
        *(f4v*)(hout + (size_t)n * 64 + ci) = o;
        *(h4v*)(hout16 + (size_t)n * 64 + ci) = __builtin_convertvector(o, h4v);
      }
    } else {
      // fused segment-mean accumulate (batch sorted): wave 0 walks the tile
      if (threadIdx.x < 64) {
        int curb = batch[n0];
        float acc = 0.0f, ca = 0.0f;
#pragma unroll 1
        for (int i = 0; i < 16; ++i) {
          int n = n0 + i;
          if (n >= N) break;
          int b = batch[n];
          if (b != curb) {
            atomicAdd(&psum[curb * 64 + lane], acc);
            if (lane == 0) atomicAdd(&pcnt[curb], ca);
            acc = 0.0f; ca = 0.0f; curb = b;
          }
          acc += oLds[i * ASTRIDE + lane];
          ca += 1.0f;
        }
        atomicAdd(&psum[curb * 64 + lane], acc);
        if (lane == 0) atomicAdd(&pcnt[curb], ca);
      }
    }
  }
}

// MLP head: 64 -> 32 -> 16 -> 1, one 64-thread block per batch element
__global__ __launch_bounds__(64) void k_head(const float* __restrict__ psum,
                                             const float* __restrict__ pcnt,
                                             const float* __restrict__ fc1W,
                                             const float* __restrict__ fc1b,
                                             const float* __restrict__ fc2W,
                                             const float* __restrict__ fc2b,
                                             const float* __restrict__ fc3W,
                                             const float* __restrict__ fc3b,
                                             float* __restrict__ out) {
  int b = blockIdx.x;
  int j = threadIdx.x;
  float c = fmaxf(pcnt[b], 1.0f);
  float p = psum[b * 64 + j] / c;
  int j1 = j & 31;
  float y1 = fc1b[j1];
#pragma unroll
  for (int k = 0; k < 64; ++k) y1 += fc1W[j1 * 64 + k] * __shfl(p, k, 64);
  y1 = fmaxf(y1, 0.0f);
  int j2 = j & 15;
  float y2 = fc2b[j2];
#pragma unroll
  for (int k = 0; k < 32; ++k) y2 += fc2W[j2 * 32 + k] * __shfl(y1, k, 64);
  y2 = fmaxf(y2, 0.0f);
  float y = 0.0f;
#pragma unroll
  for (int k = 0; k < 16; ++k) y += fc3W[k] * __shfl(y2, k, 64);
  if (j == 0) out[b] = y + fc3b[0];
}

extern "C" void kernel_launch(void* const* d_in, const int* in_sizes, int n_in,
                              void* d_out, int out_size, void* d_ws, size_t ws_size,
                              hipStream_t stream) {
  const int N = in_sizes[0];
  const int E = in_sizes[1] / 2;
  const int B = out_size;

  const int* x = (const int*)d_in[0];
  const int* eidx = (const int*)d_in[1];
  const int* batch = (const int*)d_in[3];
  const float* emb = (const float*)d_in[4];
  const float* ggcW = (const float*)d_in[7];
  const float* wih = (const float*)d_in[8];
  const float* whh = (const float*)d_in[9];
  const float* bih = (const float*)d_in[10];
  const float* bhh = (const float*)d_in[11];
  const float* fc1W = (const float*)d_in[12];
  const float* fc1b = (const float*)d_in[13];
  const float* fc2W = (const float*)d_in[14];
  const float* fc2b = (const float*)d_in[15];
  const float* fc3W = (const float*)d_in[16];
  const float* fc3b = (const float*)d_in[17];
  float* out = (float*)d_out;

  const int* srcp = eidx;
  const int* dstp = eidx + E;

  char* ws = (char*)d_ws;
  size_t off = 0;
  auto alloc = [&](size_t bytes) -> void* {
    void* p = ws + off;
    off = (off + bytes + 255) & ~(size_t)255;
    return p;
  };
  float* h0 = (float*)alloc((size_t)N * 64 * 4);
  float* h1 = (float*)alloc((size_t)N * 64 * 4);
  _Float16* h16a = (_Float16*)alloc((size_t)N * 64 * 2);
  _Float16* h16b = (_Float16*)alloc((size_t)N * 64 * 2);
  int* rowp = (int*)alloc((size_t)(N + 1) * 4);
  int* cur = (int*)alloc((size_t)N * 4);
  int* ssrc = (int*)alloc((size_t)E * 4);
  const int nC = (N + 255) / 256;
  int* part = (int*)alloc((size_t)nC * 4);
  int* coff = (int*)alloc((size_t)nC * 4);
  _Float16* Bp = (_Float16*)alloc((size_t)3 * 32768 * 2);
  float* pool = (float*)alloc((size_t)(B * 64 + B) * 4);
  float* psum = pool;
  float* pcnt = pool + (size_t)B * 64;

  // --- build CSR (dst-sorted edge list) + weight pack, once per launch ---
  hipMemsetAsync(cur, 0, (size_t)N * 4, stream);
  hipMemsetAsync(pool, 0, (size_t)(B * 64 + B) * 4, stream);
  k_embed<<<(N * 64 + 255) / 256, 256, 0, stream>>>(x, emb, h0, h16a, N);
  k_count<<<(E + 255) / 256, 256, 0, stream>>>(dstp, cur, E);
  k_scan1<<<nC, 256, 0, stream>>>(cur, part, N);
  k_scan2<<<1, 512, 0, stream>>>(part, coff, nC);
  k_scan3<<<nC, 256, 0, stream>>>(cur, coff, rowp, N, E);
  hipMemsetAsync(cur, 0, (size_t)N * 4, stream);
  k_fill<<<(E + 255) / 256, 256, 0, stream>>>(srcp, dstp, rowp, cur, ssrc, E);
  k_wpack3<<<48, 256, 0, stream>>>(wih, ggcW, whh, Bp);

  const int nTiles = (N + 15) / 16;
  const int grid = nTiles < 2048 ? nTiles : 2048;
  float* hf[2] = {h0, h1};
  _Float16* hh[2] = {h16a, h16b};
  for (int l = 0; l < 3; ++l) {
    int a = l & 1, b = 1 - a;
    k_gfu<<<grid, 256, 0, stream>>>(hf[a], hh[a], hf[b], hh[b], rowp, ssrc,
                                    Bp + (size_t)l * 32768,
                                    bih + (size_t)l * 192, bhh + (size_t)l * 192,
                                    batch, psum, pcnt, N, nTiles, l == 2 ? 1 : 0);
  }

  k_head<<<B, 64, 0, stream>>>(psum, pcnt, fc1W, fc1b, fc2W, fc2b, fc3W, fc3b, out);
}